// Round 1
// baseline (241.945 us; speedup 1.0000x reference)
//
#include <hip/hip_runtime.h>
#include <hip/hip_bf16.h>
#include <cstdint>

// Problem constants
#define B_DIM 16384
#define DX 256
#define DH 512
#define DS 128
#define DT 128
#define KDIM 1024   // DX+DH+DS+DT
#define NDIM 2048   // 4*DH
#define HOUT 512

typedef __attribute__((ext_vector_type(8))) short short8;
typedef __attribute__((ext_vector_type(4))) float floatx4;

union bf16x8 {
  short8 v;
  __hip_bfloat16 b[8];
};

__device__ __forceinline__ float fast_sigmoid(float x) {
  return 1.f / (1.f + __expf(-x));
}
__device__ __forceinline__ float fast_tanh(float x) {
  float e = __expf(-2.f * x);
  return (1.f - e) / (1.f + e);
}

// ===========================================================================
// A layout: plain row-major bf16 concat [B][1024]  (k: 0..255 x, 256..767 h,
//   768..895 s, 896..1023 t).  The GEMM computes PER-LANE global source
//   addresses for global_load_lds (only the LDS dest must be linear), so no
//   tiled re-ordering of A is needed -> pack_A is a pure streaming cvt.
//
// W layout (unchanged, stage-ready chunk order):
//   W tile (nblk,kb) = 128 packed cols x 64 k, 16 chunks of 512 bf16.
//   packed col n_local = wn*64 + g*16 + hl  <->  hh = nblk*32 + wn*16 + hl,
//   original col = g*512 + hh    (g: 0=i,1=f,2=o,3=c~)
// ===========================================================================

__global__ __launch_bounds__(256) void pack_A(
    const float* __restrict__ x, const float* __restrict__ h,
    const float* __restrict__ s, const float* __restrict__ t,
    __hip_bfloat16* __restrict__ Ap) {
  int tid = blockIdx.x * 256 + threadIdx.x;  // 0 .. B_DIM*KDIM/8-1
  int r = tid >> 7;          // row 0..16383
  int k = (tid & 127) * 8;   // 0..1016
  const float* p;
  if (k < 768) {
    p = (k < 256) ? (x + (size_t)r * DX + k) : (h + (size_t)r * DH + (k - 256));
  } else {
    p = (k < 896) ? (s + (size_t)r * DS + (k - 768)) : (t + (size_t)r * DT + (k - 896));
  }
  floatx4 v0 = *(const floatx4*)p;
  floatx4 v1 = *(const floatx4*)(p + 4);
  bf16x8 o;
#pragma unroll
  for (int j = 0; j < 4; ++j) {
    o.b[j]     = __float2bfloat16(v0[j]);
    o.b[4 + j] = __float2bfloat16(v1[j]);
  }
  *(short8*)(Ap + (size_t)tid * 8) = o.v;
}

__global__ __launch_bounds__(256) void pack_W(
    const float* __restrict__ Wx, const float* __restrict__ Wh,
    const float* __restrict__ Ws, const float* __restrict__ Wt,
    __hip_bfloat16* __restrict__ Wp) {
  int tid = blockIdx.x * 256 + threadIdx.x;  // 0 .. NDIM*KDIM/8-1
  int i = tid & 63;
  int tt = (tid >> 6) & 15;
  int tile = tid >> 10;          // nblk*16 + kb
  int kb = tile & 15, nblk = tile >> 4;
  int sp = tt >> 3, c = tt & 7;
  int nl = c * 16 + (i >> 2);    // local packed col 0..127
  int k = kb * 64 + sp * 32 + (i & 3) * 8;
  int wn = nl >> 6, g = (nl >> 4) & 3, hl = nl & 15;
  int col = g * 512 + nblk * 32 + wn * 16 + hl;
  const float* src; int kl;
  if (k < 256)      { src = Wx; kl = k; }
  else if (k < 768) { src = Wh; kl = k - 256; }
  else if (k < 896) { src = Ws; kl = k - 768; }
  else              { src = Wt; kl = k - 896; }
  bf16x8 o;
#pragma unroll
  for (int r = 0; r < 8; ++r)
    o.b[r] = __float2bfloat16(src[(size_t)(kl + r) * NDIM + col]);
  *(short8*)(Wp + (size_t)tid * 8) = o.v;
}

// ---------------------------------------------------------------------------
// m97-faithful K-loop + in-register LSTM epilogue.
// 128x128 tile, 2x2 waves, 4x4 16x16x32 MFMA acc/wave, BK=32, both operands
// via global_load_lds width=16 into 16 KB LDS, 2 barriers/iter.
// A staged straight from the row-major bf16 concat via per-lane source addrs.
// Gate g of hidden hh lives at the wave's col-tile ni=g -> register epilogue.
// ---------------------------------------------------------------------------
__global__ __launch_bounds__(256, 4) void lstm_gemm(
    const __hip_bfloat16* __restrict__ Ap, const __hip_bfloat16* __restrict__ Wp,
    const float* __restrict__ bh, const float* __restrict__ c_in,
    float* __restrict__ out) {
  __shared__ unsigned short As[128 * 32];  // 8 KB: [row][32k]
  __shared__ unsigned short Bs[128 * 32];  // 8 KB: [packed-col][32k]

  const int tid = threadIdx.x;
  const int lane = tid & 63;
  const int wid = tid >> 6;
  const int wm = wid & 1;        // row half (64 rows)
  const int wn = wid >> 1;       // col half (64 packed cols)
  const int q = lane >> 4;
  const int fr = lane & 15;
  const int mb = blockIdx.y;
  const int nblk = blockIdx.x;
  const int m0 = mb * 128;

  floatx4 acc[4][4];
#pragma unroll
  for (int i = 0; i < 4; ++i)
#pragma unroll
    for (int j = 0; j < 4; ++j) acc[i][j] = (floatx4)0.f;

  // Per-lane source offsets (in bf16 elements) for A staging:
  //   chunk = wid*2+j covers rows chunk*16 .. chunk*16+15 of the 128-row tile,
  //   lane covers row chunk*16 + (lane>>2), k-unit (lane&3)*8 within 32-k panel.
  const int arow_in_chunk = lane >> 2;
  const int akoff = (lane & 3) * 8;

  for (int p = 0; p < 32; ++p) {          // 32-k panels, k0 = p*32
    const int k0 = p * 32;
    const size_t bbase = ((size_t)((nblk * 16 + (p >> 1)) * 16 + (p & 1) * 8)) * 512;
#pragma unroll
    for (int j = 0; j < 2; ++j) {
      const int chunk = wid * 2 + j;      // wave-uniform, 0..7
      // A: per-lane source from row-major concat [B][1024]
      __builtin_amdgcn_global_load_lds(
          (const __attribute__((address_space(1))) void*)
              (Ap + (size_t)(m0 + chunk * 16 + arow_in_chunk) * KDIM + k0 + akoff),
          (__attribute__((address_space(3))) void*)&As[chunk * 512], 16, 0, 0);
      // W: chunk-flat packed layout (contiguous per lane)
      __builtin_amdgcn_global_load_lds(
          (const __attribute__((address_space(1))) void*)
              (Wp + bbase + (size_t)chunk * 512 + lane * 8),
          (__attribute__((address_space(3))) void*)&Bs[chunk * 512], 16, 0, 0);
    }
    __syncthreads();

    short8 af[4], bf[4];
#pragma unroll
    for (int i = 0; i < 4; ++i) {
      af[i] = *(const short8*)&As[(wm * 64 + i * 16 + fr) * 32 + q * 8];
      bf[i] = *(const short8*)&Bs[(wn * 64 + i * 16 + fr) * 32 + q * 8];
    }
#pragma unroll
    for (int mi = 0; mi < 4; ++mi)
#pragma unroll
      for (int ni = 0; ni < 4; ++ni)
        acc[mi][ni] = __builtin_amdgcn_mfma_f32_16x16x32_bf16(
            af[mi], bf[ni], acc[mi][ni], 0, 0, 0);
    __syncthreads();
  }

  // ---- In-register epilogue ----
  // acc[mi][g]: rows wm*64+mi*16+q*4+r, gate g of hidden hh.
  const int hh = nblk * 32 + wn * 16 + fr;
  float bias[4];
#pragma unroll
  for (int g = 0; g < 4; ++g) bias[g] = bh[g * 512 + hh];

#pragma unroll
  for (int mi = 0; mi < 4; ++mi) {
#pragma unroll
    for (int r = 0; r < 4; ++r) {
      const size_t grow = (size_t)(m0 + wm * 64 + mi * 16 + q * 4 + r);
      const float pi = acc[mi][0][r] + bias[0];
      const float pf = acc[mi][1][r] + bias[1];
      const float po = acc[mi][2][r] + bias[2];
      const float pc = acc[mi][3][r] + bias[3];
      const float ig = fast_sigmoid(pi);
      const float fg = fast_sigmoid(pf);
      const float og = fast_sigmoid(po);
      const float cg = fast_tanh(pc);
      const float cc = fg * c_in[grow * HOUT + hh] + ig * cg;
      out[grow * HOUT + hh] = fast_tanh(og * cc);  // faithful: tanh(o*c_new)
      out[(size_t)B_DIM * HOUT + grow * HOUT + hh] = cc;
    }
  }
}

// ---------------------------------------------------------------------------
extern "C" void kernel_launch(void* const* d_in, const int* in_sizes, int n_in,
                              void* d_out, int out_size, void* d_ws, size_t ws_size,
                              hipStream_t stream) {
  const float* x  = (const float*)d_in[0];
  const float* h  = (const float*)d_in[1];
  const float* c  = (const float*)d_in[2];
  const float* sp = (const float*)d_in[3];
  const float* tp = (const float*)d_in[4];
  const float* Wx = (const float*)d_in[5];
  const float* Wh = (const float*)d_in[6];
  const float* bh = (const float*)d_in[7];
  const float* Ws = (const float*)d_in[8];
  const float* Wt = (const float*)d_in[9];
  float* out = (float*)d_out;

  __hip_bfloat16* Ap = (__hip_bfloat16*)d_ws;                                     // 32 MB
  __hip_bfloat16* Wp = (__hip_bfloat16*)((char*)d_ws + (size_t)B_DIM * KDIM * 2); // 4 MB

  pack_A<<<dim3(B_DIM * KDIM / 8 / 256), dim3(256), 0, stream>>>(x, h, sp, tp, Ap);
  pack_W<<<dim3(NDIM * KDIM / 8 / 256), dim3(256), 0, stream>>>(Wx, Wh, Ws, Wt, Wp);
  lstm_gemm<<<dim3(NDIM / 128, B_DIM / 128), dim3(256), 0, stream>>>(Ap, Wp, bh, c, out);
}